// Round 10
// baseline (62.812 us; speedup 1.0000x reference)
//
#include <hip/hip_runtime.h>
#include <hip/hip_bf16.h>
#include <stdint.h>

#define HID 768

typedef short bf16x8 __attribute__((ext_vector_type(8)));
typedef unsigned short ushort8_t __attribute__((ext_vector_type(8)));
typedef float f32x4 __attribute__((ext_vector_type(4)));
typedef unsigned int uint2_t __attribute__((ext_vector_type(2)));

// packed f32x2 -> bf16x2 (compiler emits v_cvt_pk_bf16_f32)
__device__ __forceinline__ unsigned int pack2bf(float x, float y) {
    __hip_bfloat162 h = __float22bfloat162_rn(make_float2(x, y));
    return *reinterpret_cast<unsigned int*>(&h);
}
__device__ __forceinline__ unsigned short f2bf1(float x) {
    __hip_bfloat16 h = __float2bfloat16(x);
    return *reinterpret_cast<unsigned short*>(&h);
}

// async global->LDS, 16B per lane; lds dest = wave-uniform base + lane*16
__device__ __forceinline__ void gload_lds16(const void* g, void* l) {
    __builtin_amdgcn_global_load_lds(
        (const __attribute__((address_space(1))) unsigned int*)g,
        (__attribute__((address_space(3))) unsigned int*)l, 16, 0, 0);
}

// ---------------- merged transpose+cast: 4 regions, f32 [R][C] -> bf16 [C][R] ----
__global__ void prep_k(const float* __restrict__ W1,
                       const float* __restrict__ W2,
                       const float* __restrict__ W3,
                       unsigned short* __restrict__ W1x,
                       unsigned short* __restrict__ W2t,
                       unsigned short* __restrict__ W3t) {
    __shared__ float t[32][33];
    int b = blockIdx.x;
    const float* in; unsigned short* op; int R, C, bx, by;
    if (b < 576)       { in = W1;           op = W1x;           R = 768; C = 768; bx = b % 24;        by = b / 24; }
    else if (b < 1152) { in = W1 + 768*768; op = W1x + 768*768; R = 768; C = 768; bx = (b-576) % 24;  by = (b-576) / 24; }
    else if (b < 1440) { in = W2;           op = W2t;           R = 768; C = 384; bx = (b-1152) % 12; by = (b-1152) / 12; }
    else               { in = W3;           op = W3t;           R = 384; C = 128; bx = (b-1440) % 4;  by = (b-1440) / 4; }
    int c0 = bx * 32, r0 = by * 32;
    int tx = threadIdx.x, ty = threadIdx.y;   // 32 x 8
    #pragma unroll
    for (int k = 0; k < 4; ++k)
        t[ty + 8*k][tx] = in[(size_t)(r0 + ty + 8*k) * C + c0 + tx];
    __syncthreads();
    #pragma unroll
    for (int k = 0; k < 4; ++k)
        op[(size_t)(c0 + ty + 8*k) * R + r0 + tx] = f2bf1(t[tx][ty + 8*k]);
}

// ---------------- AB = feat @ W1x^T (+b1 on A half) : M=256, N=1536, K=768 ------
// 96 blocks of 64m x 64n; 4 waves, wave n-band = wid*16
__launch_bounds__(256, 2)
__global__ void ab_gemm_k(const float* __restrict__ F,
                          const unsigned short* __restrict__ W,
                          const float* __restrict__ b1,
                          float* __restrict__ AB) {
    __shared__ alignas(1024) unsigned short fl[2][64*72];   // 18,432 B
    __shared__ alignas(1024) unsigned short wl[2][64*64];   // 16,384 B (swizzled)
    int tid = threadIdx.x;
    int lane = tid & 63, wid = tid >> 6;   // 4 waves
    int n0 = blockIdx.x * 64, m0 = blockIdx.y * 64;
    f32x4 acc[4] = {};
    float4 rf[2][2];

    #pragma unroll
    for (int s = 0; s < 2; ++s) {          // W tile 64x64 -> 8 chunks of 1024B
        int chunk = wid*2 + s;
        int row = chunk*8 + (lane>>3);
        int cg = (lane&7) ^ (row&7);
        gload_lds16(W + (size_t)(n0 + row)*HID + cg*8, (char*)wl[0] + chunk*1024);
    }
    #pragma unroll
    for (int s = 0; s < 2; ++s) {          // F tile 64x64 f32
        int idx = tid + s*256;
        int r = idx >> 3, c8 = idx & 7;
        const float4* src = (const float4*)(F + (size_t)(m0 + r)*HID + c8*8);
        rf[s][0] = src[0]; rf[s][1] = src[1];
    }
    #pragma unroll
    for (int s = 0; s < 2; ++s) {
        int idx = tid + s*256;
        int r = idx >> 3, c8 = idx & 7;
        unsigned int us32[4] = { pack2bf(rf[s][0].x, rf[s][0].y), pack2bf(rf[s][0].z, rf[s][0].w),
                                 pack2bf(rf[s][1].x, rf[s][1].y), pack2bf(rf[s][1].z, rf[s][1].w) };
        *(ushort8_t*)(fl[0] + r*72 + c8*8) = *(ushort8_t*)us32;
    }
    __syncthreads();

    for (int t = 0; t < 12; ++t) {
        int cur = t & 1;
        if (t < 11) {
            int kk = (t+1) * 64;
            #pragma unroll
            for (int s = 0; s < 2; ++s) {
                int chunk = wid*2 + s;
                int row = chunk*8 + (lane>>3);
                int cg = (lane&7) ^ (row&7);
                gload_lds16(W + (size_t)(n0 + row)*HID + kk + cg*8, (char*)wl[cur^1] + chunk*1024);
            }
            #pragma unroll
            for (int s = 0; s < 2; ++s) {
                int idx = tid + s*256;
                int r = idx >> 3, c8 = idx & 7;
                const float4* src = (const float4*)(F + (size_t)(m0 + r)*HID + kk + c8*8);
                rf[s][0] = src[0]; rf[s][1] = src[1];
            }
        }
        __builtin_amdgcn_s_setprio(1);
        #pragma unroll
        for (int ks = 0; ks < 2; ++ks) {
            bf16x8 a[4], b;
            #pragma unroll
            for (int fm = 0; fm < 4; ++fm)
                a[fm] = *(const bf16x8*)(fl[cur] + (fm*16 + (lane&15))*72 + ks*32 + (lane>>4)*8);
            {
                int n = wid*16 + (lane&15);
                int g = ks*4 + (lane>>4);
                b = *(const bf16x8*)(wl[cur] + n*64 + ((g ^ (n&7)) * 8));
            }
            #pragma unroll
            for (int fm = 0; fm < 4; ++fm)
                acc[fm] = __builtin_amdgcn_mfma_f32_16x16x32_bf16(a[fm], b, acc[fm], 0,0,0);
        }
        __builtin_amdgcn_s_setprio(0);
        if (t < 11) {
            #pragma unroll
            for (int s = 0; s < 2; ++s) {
                int idx = tid + s*256;
                int r = idx >> 3, c8 = idx & 7;
                unsigned int us32[4] = { pack2bf(rf[s][0].x, rf[s][0].y), pack2bf(rf[s][0].z, rf[s][0].w),
                                         pack2bf(rf[s][1].x, rf[s][1].y), pack2bf(rf[s][1].z, rf[s][1].w) };
                *(ushort8_t*)(fl[cur^1] + r*72 + c8*8) = *(ushort8_t*)us32;
            }
        }
        __syncthreads();
    }
    #pragma unroll
    for (int fm = 0; fm < 4; ++fm)
        #pragma unroll
        for (int q = 0; q < 4; ++q) {
            int row = m0 + fm*16 + (lane>>4)*4 + q;
            int col = n0 + wid*16 + (lane&15);
            float bias = (col < 768) ? b1[col] : 0.0f;
            AB[(size_t)row*1536 + col] = acc[fm][q] + bias;
        }
}

// ---------------- fused pair MLP: 64 pairs/block, 510 blocks, 2 blocks/CU -------
// 512 thr = 8 waves; K-step 32; EVERYTHING double-buffered; 1 barrier/step.
// LDS 65 KB -> 2 blocks/CU; sibling block absorbs barrier skew + load latency.
__launch_bounds__(512, 4)
__global__ void fused_k(const float* __restrict__ AB,            // [256][1536] f32
                        const unsigned short* __restrict__ W2t,  // [384][768] bf16
                        const float* __restrict__ b2,            // [384]
                        const unsigned short* __restrict__ W3t,  // [128][384] bf16
                        const float* __restrict__ b3,            // [128]
                        float* __restrict__ out) {               // [32640][128] f32
    __shared__ alignas(1024) char smem[66560];
    unsigned short* h1_0 = (unsigned short*)(smem);           // [64][40]  (5,120 B)
    unsigned short* h1_1 = (unsigned short*)(smem + 5120);    // [64][40]
    unsigned short* w2_0 = (unsigned short*)(smem + 10240);   // [384][32] swz (24,576 B)
    unsigned short* w2_1 = (unsigned short*)(smem + 34816);   // [384][32] swz
    unsigned short* h2   = (unsigned short*)(smem);           // [64][392] phase B (50,176 B)
    unsigned short* w3_0 = (unsigned short*)(smem + 50176);   // [128][32] swz (8,192 B)
    unsigned short* w3_1 = (unsigned short*)(smem + 58368);   // [128][32] swz

    int tid = threadIdx.x;
    int lane = tid & 63, wid = tid >> 6;   // 8 waves
    int wc = wid;                          // phase A: 1 x 8 grid, wave tile 64 x 48
    int p0 = blockIdx.x * 64;

    // pair indices for my h1-gen row (8 threads/row, 4 cols each)
    int hr = tid >> 3;                     // 0..63
    int hcq = (tid & 7) * 4;               // col chunk (4 f32) within 32
    int p = p0 + hr;
    float sdisc = sqrtf((float)(511*511 - 8*p));
    int i_me = (int)((511.0f - sdisc) * 0.5f);
    if (i_me < 0) i_me = 0; if (i_me > 254) i_me = 254;
    while (i_me < 255 && (i_me+1)*255 - (i_me+1)*i_me/2 <= p) ++i_me;
    while (i_me > 0 && i_me*255 - i_me*(i_me-1)/2 > p) --i_me;
    int j_me = i_me + 1 + (p - (i_me*255 - i_me*(i_me-1)/2));

    const float* abI = AB + (size_t)i_me*1536 + hcq;
    const float* abJ = AB + (size_t)j_me*1536 + 768 + hcq;

    float4 ra, rb;
    f32x4 acc2[4][3] = {};

#define H1_LOAD(KK) { ra = *(const float4*)(abI + (KK)); rb = *(const float4*)(abJ + (KK)); }

#define H1_PACK(H1N) { \
    uint2_t uu_; \
    uu_[0] = pack2bf(fmaxf(ra.x + rb.x, 0.f), fmaxf(ra.y + rb.y, 0.f)); \
    uu_[1] = pack2bf(fmaxf(ra.z + rb.z, 0.f), fmaxf(ra.w + rb.w, 0.f)); \
    *(uint2_t*)((H1N) + hr*40 + (tid&7)*4) = uu_; }

// stage w2 K-slice [384 rows][32 cols]: 24 chunks of 1024B, 3 per wave.
// chunk = 16 rows; lane covers row chunk*16+(lane>>2), quarter lane&3;
// source quarter pre-swizzled: cg = (lane&3) ^ ((lane>>3)&3)  [== (n>>1)&3]
#define STAGE_W2(DST, KK) { \
    _Pragma("unroll") for (int s_ = 0; s_ < 3; ++s_) { \
        int chunk_ = wid*3 + s_; \
        int row_ = chunk_*16 + (lane>>2); \
        int cg_ = (lane&3) ^ ((lane>>3)&3); \
        gload_lds16(W2t + (size_t)row_*HID + (KK) + cg_*8, (char*)(DST) + chunk_*1024); } }

#define MFMA_STEP(H1C, W2C) { \
    __builtin_amdgcn_s_setprio(1); \
    bf16x8 a_[4], b_[3]; \
    _Pragma("unroll") for (int fm_ = 0; fm_ < 4; ++fm_) \
        a_[fm_] = *(const bf16x8*)((H1C) + (fm_*16 + (lane&15))*40 + (lane>>4)*8); \
    _Pragma("unroll") for (int fn_ = 0; fn_ < 3; ++fn_) { \
        int n_ = wc*48 + fn_*16 + (lane&15); \
        b_[fn_] = *(const bf16x8*)((W2C) + n_*32 + (((lane>>4) ^ ((n_>>1)&3)) * 8)); } \
    _Pragma("unroll") for (int fm_ = 0; fm_ < 4; ++fm_) \
    _Pragma("unroll") for (int fn_ = 0; fn_ < 3; ++fn_) \
        acc2[fm_][fn_] = __builtin_amdgcn_mfma_f32_16x16x32_bf16(a_[fm_], b_[fn_], acc2[fm_][fn_], 0,0,0); \
    __builtin_amdgcn_s_setprio(0); }

#define ENDBAR() { asm volatile("s_waitcnt vmcnt(0) lgkmcnt(0)" ::: "memory"); \
    __builtin_amdgcn_sched_barrier(0); __builtin_amdgcn_s_barrier(); }

    // ---- prologue: AB(0) -> pack h1(0); stage w2(0)
    H1_LOAD(0);
    __builtin_amdgcn_sched_barrier(0);
    STAGE_W2(w2_0, 0);
    __builtin_amdgcn_sched_barrier(0);
    H1_PACK(h1_0);                          // auto-wait vmcnt(3): w2(0) stays in flight
    ENDBAR();

    // ---- phase A: 24 K-steps of 32, explicit even/odd; 1 barrier/step
    for (int t2 = 0; t2 < 12; ++t2) {
        int tE = 2*t2, tO = 2*t2 + 1;
        // even step: read h1_0/w2_0, prefetch into h1_1/w2_1
        H1_LOAD((tE+1) * 32);
        __builtin_amdgcn_sched_barrier(0);
        STAGE_W2(w2_1, (tE+1) * 32);
        __builtin_amdgcn_sched_barrier(0);
        MFMA_STEP(h1_0, w2_0);
        H1_PACK(h1_1);                      // auto-wait vmcnt(3)
        ENDBAR();
        // odd step: read h1_1/w2_1, prefetch into h1_0/w2_0
        if (tO < 23) {
            H1_LOAD((tO+1) * 32);
            __builtin_amdgcn_sched_barrier(0);
            STAGE_W2(w2_0, (tO+1) * 32);
            __builtin_amdgcn_sched_barrier(0);
            MFMA_STEP(h1_1, w2_1);
            H1_PACK(h1_0);
            ENDBAR();
        } else {
            MFMA_STEP(h1_1, w2_1);
            ENDBAR();                       // all h1/w2 reads done -> reuse as h2
        }
    }

    // ---- phase B: h2 = relu(acc2+b2) -> [64][392]; w3 dbuf; grid 2x4 (32x32)
    int wrB = wid >> 2, wcB = wid & 3;

#define STAGE_W3(DST, KT) { \
    int row_ = wid*16 + (lane>>2); \
    int cg_ = (lane&3) ^ ((lane>>3)&3); \
    gload_lds16(W3t + (size_t)row_*384 + (KT)*32 + cg_*8, (char*)(DST) + wid*1024); }

#define MFMA_B(W3C, KT) { \
    __builtin_amdgcn_s_setprio(1); \
    bf16x8 a_[2], b_[2]; \
    _Pragma("unroll") for (int fm_ = 0; fm_ < 2; ++fm_) \
        a_[fm_] = *(const bf16x8*)(h2 + (wrB*32 + fm_*16 + (lane&15))*392 + (KT)*32 + (lane>>4)*8); \
    _Pragma("unroll") for (int fn_ = 0; fn_ < 2; ++fn_) { \
        int n_ = wcB*32 + fn_*16 + (lane&15); \
        b_[fn_] = *(const bf16x8*)((W3C) + n_*32 + (((lane>>4) ^ ((n_>>1)&3)) * 8)); } \
    _Pragma("unroll") for (int fm_ = 0; fm_ < 2; ++fm_) \
    _Pragma("unroll") for (int fn_ = 0; fn_ < 2; ++fn_) \
        acc3[fm_][fn_] = __builtin_amdgcn_mfma_f32_16x16x32_bf16(a_[fm_], b_[fn_], acc3[fm_][fn_], 0,0,0); \
    __builtin_amdgcn_s_setprio(0); }

    f32x4 acc3[2][2] = {};
    STAGE_W3(w3_0, 0);
    // h2 writes (overlay of phase-A region — safe after last ENDBAR)
    #pragma unroll
    for (int fn = 0; fn < 3; ++fn) {
        int col = wc*48 + fn*16 + (lane&15);
        float bb = b2[col];
        #pragma unroll
        for (int fm = 0; fm < 4; ++fm)
            #pragma unroll
            for (int q = 0; q < 4; ++q) {
                int row = fm*16 + (lane>>4)*4 + q;
                h2[row*392 + col] = f2bf1(fmaxf(acc2[fm][fn][q] + bb, 0.f));
            }
    }
    ENDBAR();

    for (int k2 = 0; k2 < 6; ++k2) {
        int kE = 2*k2, kO = 2*k2 + 1;
        STAGE_W3(w3_1, kE+1);
        MFMA_B(w3_0, kE);
        ENDBAR();
        if (kO < 11) {
            STAGE_W3(w3_0, kO+1);
            MFMA_B(w3_1, kO);
            ENDBAR();
        } else {
            MFMA_B(w3_1, kO);
        }
    }

    #pragma unroll
    for (int fm = 0; fm < 2; ++fm)
        #pragma unroll
        for (int fn = 0; fn < 2; ++fn) {
            int col = wcB*32 + fn*16 + (lane&15);
            float bb = b3[col];
            #pragma unroll
            for (int q = 0; q < 4; ++q) {
                int row = p0 + wrB*32 + fm*16 + (lane>>4)*4 + q;
                out[(size_t)row*128 + col] = acc3[fm][fn][q] + bb;
            }
        }
}

extern "C" void kernel_launch(void* const* d_in, const int* in_sizes, int n_in,
                              void* d_out, int out_size, void* d_ws, size_t ws_size,
                              hipStream_t stream) {
    const float* feat = (const float*)d_in[0];  // [256][768]
    const float* W1   = (const float*)d_in[1];  // [1536][768]
    const float* b1   = (const float*)d_in[2];  // [768]
    const float* W2   = (const float*)d_in[3];  // [768][384]
    const float* b2   = (const float*)d_in[4];  // [384]
    const float* W3   = (const float*)d_in[5];  // [384][128]
    const float* b3   = (const float*)d_in[6];  // [128]
    float* out = (float*)d_out;

    char* ws = (char*)d_ws;
    unsigned short* W1x = (unsigned short*)(ws + 0);        // 1536*768*2 = 2,359,296
    unsigned short* W2t = (unsigned short*)(ws + 2359296);  // 384*768*2  =   589,824
    unsigned short* W3t = (unsigned short*)(ws + 2949120);  // 128*384*2  =    98,304
    float*          AB  = (float*)        (ws + 3047424);   // 256*1536*4 = 1,572,864

    prep_k<<<1488, dim3(32,8), 0, stream>>>(W1, W2, W3, W1x, W2t, W3t);
    ab_gemm_k<<<dim3(24,4), 256, 0, stream>>>(feat, W1x, b1, AB);
    fused_k<<<510, 512, 0, stream>>>(AB, W2t, b2, W3t, b3, out);
}

// Round 12
// 48.440 us; speedup vs baseline: 1.2967x; 1.2967x over previous
//
#include <hip/hip_runtime.h>
#include <hip/hip_bf16.h>
#include <stdint.h>

#define HID 768

typedef short bf16x8 __attribute__((ext_vector_type(8)));
typedef unsigned short ushort8_t __attribute__((ext_vector_type(8)));
typedef float f32x4 __attribute__((ext_vector_type(4)));

// packed f32x2 -> bf16x2 (compiler emits v_cvt_pk_bf16_f32)
__device__ __forceinline__ unsigned int pack2bf(float x, float y) {
    __hip_bfloat162 h = __float22bfloat162_rn(make_float2(x, y));
    return *reinterpret_cast<unsigned int*>(&h);
}
__device__ __forceinline__ unsigned short f2bf1(float x) {
    __hip_bfloat16 h = __float2bfloat16(x);
    return *reinterpret_cast<unsigned short*>(&h);
}

// async global->LDS, 16B per lane; lds dest = wave-uniform base + lane*16
__device__ __forceinline__ void gload_lds16(const void* g, void* l) {
    __builtin_amdgcn_global_load_lds(
        (const __attribute__((address_space(1))) unsigned int*)g,
        (__attribute__((address_space(3))) unsigned int*)l, 16, 0, 0);
}

// ---------------- combo: blocks 0..95 = AB gemm (W1 consumed untransposed);
//                  blocks 96..431 = W2/W3 transpose+cast.
// Sync: ONLY __syncthreads() (drains vmcnt+lgkmcnt) — no hand-counted waits.
__launch_bounds__(256, 2)
__global__ void prep_ab_k(const float* __restrict__ F,     // feat [256][768]
                          const float* __restrict__ W1,    // [1536][768] f32
                          const float* __restrict__ b1,    // [768]
                          const float* __restrict__ W2,    // [768][384]
                          const float* __restrict__ W3,    // [384][128]
                          unsigned short* __restrict__ W2t,
                          unsigned short* __restrict__ W3t,
                          float* __restrict__ AB) {        // [256][1536]
    __shared__ alignas(1024) char smem[51200];
    int b = blockIdx.x;

    if (b >= 96) {
        // ---- transpose path: f32 [R][C] -> bf16 [C][R]
        float (*t)[33] = (float(*)[33])smem;
        int b2 = b - 96;
        const float* in; unsigned short* op; int R, C, bx, by;
        if (b2 < 288) { in = W2; op = W2t; R = 768; C = 384; bx = b2 % 12; by = b2 / 12; }
        else          { int b3i = b2 - 288; in = W3; op = W3t; R = 384; C = 128; bx = b3i % 4; by = b3i / 4; }
        int c0 = bx * 32, r0 = by * 32;
        int tx = threadIdx.x & 31, ty = threadIdx.x >> 5;   // 32 x 8
        #pragma unroll
        for (int k = 0; k < 4; ++k)
            t[ty + 8*k][tx] = in[(size_t)(r0 + ty + 8*k) * C + c0 + tx];
        __syncthreads();
        #pragma unroll
        for (int k = 0; k < 4; ++k)
            op[(size_t)(c0 + ty + 8*k) * R + r0 + tx] = f2bf1(t[tx][ty + 8*k]);
        return;
    }

    // ---- gemm path: AB tile 64m x 64n, K=768
    unsigned short* fl = (unsigned short*)smem;             // 2 x [64][72] bf16 (18,432 B)
    float*          wt = (float*)(smem + 18432);            // 2 x [64][64] f32  (32,768 B)

    int tid = threadIdx.x;
    int lane = tid & 63, wid = tid >> 6;   // 4 waves
    int bx = b % 24, by = b / 24;
    int n0 = bx * 64, m0 = by * 64;
    const float* Wsrc = W1 + (n0 < 768 ? 0 : (size_t)768*768);
    int cb = (n0 < 768) ? n0 : n0 - 768;

    f32x4 acc[4] = {};
    float4 rf[2][2];

    // stage wt[0]: k-rows 0..63, cols cb..cb+63 (4 k-rows per 1KB chunk)
    #pragma unroll
    for (int s = 0; s < 4; ++s) {
        int chunk = wid*4 + s;                  // 16 chunks
        int rk = chunk*4 + (lane>>4);
        int c16 = (lane&15)*4;
        gload_lds16(Wsrc + (size_t)rk*HID + cb + c16, (char*)wt + chunk*1024);
    }
    #pragma unroll
    for (int s = 0; s < 2; ++s) {               // F tile 64x64 f32 -> regs
        int idx = tid + s*256;
        int r = idx >> 3, c8 = idx & 7;
        const float4* src = (const float4*)(F + (size_t)(m0 + r)*HID + c8*8);
        rf[s][0] = src[0]; rf[s][1] = src[1];
    }
    #pragma unroll
    for (int s = 0; s < 2; ++s) {
        int idx = tid + s*256;
        int r = idx >> 3, c8 = idx & 7;
        unsigned int us32[4] = { pack2bf(rf[s][0].x, rf[s][0].y), pack2bf(rf[s][0].z, rf[s][0].w),
                                 pack2bf(rf[s][1].x, rf[s][1].y), pack2bf(rf[s][1].z, rf[s][1].w) };
        *(ushort8_t*)(fl + r*72 + c8*8) = *(ushort8_t*)us32;
    }
    __syncthreads();

    for (int t = 0; t < 12; ++t) {
        int cur = t & 1;
        unsigned short* flc = fl + cur*(64*72);
        float* wtc = wt + cur*(64*64);
        if (t < 11) {
            int kk = (t+1) * 64;
            float* wtn = wt + (cur^1)*(64*64);
            #pragma unroll
            for (int s = 0; s < 4; ++s) {
                int chunk = wid*4 + s;
                int rk = chunk*4 + (lane>>4);
                int c16 = (lane&15)*4;
                gload_lds16(Wsrc + (size_t)(kk + rk)*HID + cb + c16, (char*)wtn + chunk*1024);
            }
            #pragma unroll
            for (int s = 0; s < 2; ++s) {
                int idx = tid + s*256;
                int r = idx >> 3, c8 = idx & 7;
                const float4* src = (const float4*)(F + (size_t)(m0 + r)*HID + kk + c8*8);
                rf[s][0] = src[0]; rf[s][1] = src[1];
            }
        }
        __builtin_amdgcn_s_setprio(1);
        #pragma unroll
        for (int ks = 0; ks < 2; ++ks) {
            bf16x8 a[4], bfrag;
            #pragma unroll
            for (int fm = 0; fm < 4; ++fm)
                a[fm] = *(const bf16x8*)(flc + (fm*16 + (lane&15))*72 + ks*32 + (lane>>4)*8);
            {   // b-frag: column gather from k-major f32 tile + pack to bf16
                int nl = wid*16 + (lane&15);
                int k0 = ks*32 + (lane>>4)*8;
                float v[8];
                #pragma unroll
                for (int d = 0; d < 8; ++d)
                    v[d] = wtc[(k0 + d)*64 + nl];
                unsigned int us[4] = { pack2bf(v[0],v[1]), pack2bf(v[2],v[3]),
                                       pack2bf(v[4],v[5]), pack2bf(v[6],v[7]) };
                bfrag = *(bf16x8*)us;
            }
            #pragma unroll
            for (int fm = 0; fm < 4; ++fm)
                acc[fm] = __builtin_amdgcn_mfma_f32_16x16x32_bf16(a[fm], bfrag, acc[fm], 0,0,0);
        }
        __builtin_amdgcn_s_setprio(0);
        if (t < 11) {
            unsigned short* fln = fl + (cur^1)*(64*72);
            #pragma unroll
            for (int s = 0; s < 2; ++s) {
                int idx = tid + s*256;
                int r = idx >> 3, c8 = idx & 7;
                unsigned int us32[4] = { pack2bf(rf[s][0].x, rf[s][0].y), pack2bf(rf[s][0].z, rf[s][0].w),
                                         pack2bf(rf[s][1].x, rf[s][1].y), pack2bf(rf[s][1].z, rf[s][1].w) };
                *(ushort8_t*)(fln + r*72 + c8*8) = *(ushort8_t*)us32;
            }
        }
        __syncthreads();
    }
    #pragma unroll
    for (int fm = 0; fm < 4; ++fm)
        #pragma unroll
        for (int q = 0; q < 4; ++q) {
            int row = m0 + fm*16 + (lane>>4)*4 + q;
            int col = n0 + wid*16 + (lane&15);
            float bias = (col < 768) ? b1[col] : 0.0f;   // fold b1 into A half
            AB[(size_t)row*1536 + col] = acc[fm][q] + bias;
        }
}

// ---------------- fused pair MLP: 16 waves, plain __syncthreads pipeline --------
// phase A: 2x8 wave grid (64x48 tiles), dbuf h1 + dbuf w2 (gload_lds, swizzled);
// phase B: 4x4 grid (32x32), dbuf w3. NO inline-asm waitcnt anywhere.
__launch_bounds__(1024, 1)
__global__ void fused_k(const float* __restrict__ AB,            // [256][1536] f32
                        const unsigned short* __restrict__ W2t,  // [384][768] bf16
                        const float* __restrict__ b2,            // [384]
                        const unsigned short* __restrict__ W3t,  // [128][384] bf16
                        const float* __restrict__ b3,            // [128]
                        float* __restrict__ out) {               // [32640][128] f32
    __shared__ alignas(1024) char smem[135168];
    unsigned short* h1b = (unsigned short*)(smem);            // 2 x [128][72]   (36,864 B)
    unsigned short* w2b = (unsigned short*)(smem + 36864);    // 2 x [384][64] swizzled (98,304 B)
    unsigned short* h2  = (unsigned short*)(smem);            // [128][392] phase B (reuse)
    unsigned short* w3b = (unsigned short*)(smem + 100352);   // 2 x [128][64] swizzled (32,768 B)

    int tid = threadIdx.x;
    int lane = tid & 63, wid = tid >> 6;   // 16 waves
    int wr = wid >> 3, wc = wid & 7;       // phase A: 2 x 8 wave grid
    int p0 = blockIdx.x * 128;

    int hr = tid >> 3;                     // 0..127
    int hc = (tid & 7) * 8;                // col chunk within 64
    int p = p0 + hr;
    float sdisc = sqrtf((float)(511*511 - 8*p));
    int i_me = (int)((511.0f - sdisc) * 0.5f);
    if (i_me < 0) i_me = 0; if (i_me > 254) i_me = 254;
    while (i_me < 255 && (i_me+1)*255 - (i_me+1)*i_me/2 <= p) ++i_me;
    while (i_me > 0 && i_me*255 - i_me*(i_me-1)/2 > p) --i_me;
    int j_me = i_me + 1 + (p - (i_me*255 - i_me*(i_me-1)/2));

    float4 ra[2], rb[2];

    // ---- prologue: h1(0) pack; w2(0) gloads; one barrier
    {
        const float4* pa = (const float4*)(AB + (size_t)i_me*1536 + hc);
        const float4* pb = (const float4*)(AB + (size_t)j_me*1536 + 768 + hc);
        ra[0] = pa[0]; ra[1] = pa[1]; rb[0] = pb[0]; rb[1] = pb[1];
        unsigned int us32[4];
        #pragma unroll
        for (int u = 0; u < 2; ++u) {
            us32[u*2+0] = pack2bf(fmaxf(ra[u].x + rb[u].x, 0.f), fmaxf(ra[u].y + rb[u].y, 0.f));
            us32[u*2+1] = pack2bf(fmaxf(ra[u].z + rb[u].z, 0.f), fmaxf(ra[u].w + rb[u].w, 0.f));
        }
        *(ushort8_t*)(h1b + hr*72 + hc) = *(ushort8_t*)us32;
    }
    #pragma unroll
    for (int s = 0; s < 3; ++s) {
        int chunk = wid*3 + s;                 // 48 chunks of 1024B
        int row = chunk*8 + (lane>>3);
        int cg = (lane&7) ^ (row&7);
        gload_lds16(W2t + (size_t)row*HID + cg*8, (char*)w2b + chunk*1024);
    }
    __syncthreads();

    f32x4 acc2[4][3] = {};
    for (int t = 0; t < 12; ++t) {
        int cur = t & 1;
        unsigned short* h1c = h1b + cur * (128*72);
        unsigned short* w2c = w2b + cur * (384*64);
        if (t < 11) {                          // issue next-step loads BEFORE compute
            int kk = (t+1) * 64;
            unsigned short* w2n = w2b + (cur^1) * (384*64);
            #pragma unroll
            for (int s = 0; s < 3; ++s) {
                int chunk = wid*3 + s;
                int row = chunk*8 + (lane>>3);
                int cg = (lane&7) ^ (row&7);
                gload_lds16(W2t + (size_t)row*HID + kk + cg*8, (char*)w2n + chunk*1024);
            }
            const float4* pa = (const float4*)(AB + (size_t)i_me*1536 + kk + hc);
            const float4* pb = (const float4*)(AB + (size_t)j_me*1536 + 768 + kk + hc);
            ra[0] = pa[0]; ra[1] = pa[1]; rb[0] = pb[0]; rb[1] = pb[1];
        }
        __builtin_amdgcn_s_setprio(1);
        #pragma unroll
        for (int ks = 0; ks < 2; ++ks) {
            bf16x8 a[4], bfr[3];
            #pragma unroll
            for (int fm = 0; fm < 4; ++fm)
                a[fm] = *(const bf16x8*)(h1c + (wr*64 + fm*16 + (lane&15))*72 + ks*32 + (lane>>4)*8);
            #pragma unroll
            for (int fn = 0; fn < 3; ++fn) {
                int n = wc*48 + fn*16 + (lane&15);
                int g = ks*4 + (lane>>4);
                bfr[fn] = *(const bf16x8*)(w2c + n*64 + ((g ^ (n&7)) * 8));
            }
            #pragma unroll
            for (int fm = 0; fm < 4; ++fm)
                #pragma unroll
                for (int fn = 0; fn < 3; ++fn)
                    acc2[fm][fn] = __builtin_amdgcn_mfma_f32_16x16x32_bf16(a[fm], bfr[fn], acc2[fm][fn], 0,0,0);
        }
        __builtin_amdgcn_s_setprio(0);
        if (t < 11) {                          // pack prefetched AB -> h1[next]
            unsigned short* h1n = h1b + (cur^1) * (128*72);
            unsigned int us32[4];
            #pragma unroll
            for (int u = 0; u < 2; ++u) {
                us32[u*2+0] = pack2bf(fmaxf(ra[u].x + rb[u].x, 0.f), fmaxf(ra[u].y + rb[u].y, 0.f));
                us32[u*2+1] = pack2bf(fmaxf(ra[u].z + rb[u].z, 0.f), fmaxf(ra[u].w + rb[u].w, 0.f));
            }
            *(ushort8_t*)(h1n + hr*72 + hc) = *(ushort8_t*)us32;
        }
        __syncthreads();
    }

    // ---- phase transition: h2 = relu(acc2 + b2) -> [128][392]; stage w3(0)
    #pragma unroll
    for (int fn = 0; fn < 3; ++fn) {
        int col = wc*48 + fn*16 + (lane&15);
        float bb = b2[col];
        #pragma unroll
        for (int fm = 0; fm < 4; ++fm)
            #pragma unroll
            for (int q = 0; q < 4; ++q) {
                int row = wr*64 + fm*16 + (lane>>4)*4 + q;
                h2[row*392 + col] = f2bf1(fmaxf(acc2[fm][fn][q] + bb, 0.f));
            }
    }
    {
        int chunk = wid;                       // 16 chunks, 1 per wave
        int row = chunk*8 + (lane>>3);
        int cg = (lane&7) ^ (row&7);
        gload_lds16(W3t + (size_t)row*384 + cg*8, (char*)w3b + chunk*1024);
    }
    __syncthreads();

    // ---- phase B: 4x4 wave grid, tile 32x32, dbuf w3
    int wrB = wid >> 2, wcB = wid & 3;
    f32x4 acc3[2][2] = {};
    for (int kt = 0; kt < 6; ++kt) {
        int cur = kt & 1;
        unsigned short* w3c = w3b + cur * (128*64);
        if (kt < 5) {
            unsigned short* w3n = w3b + (cur^1) * (128*64);
            int chunk = wid;
            int row = chunk*8 + (lane>>3);
            int cg = (lane&7) ^ (row&7);
            gload_lds16(W3t + (size_t)row*384 + (kt+1)*64 + cg*8, (char*)w3n + chunk*1024);
        }
        __builtin_amdgcn_s_setprio(1);
        #pragma unroll
        for (int ks = 0; ks < 2; ++ks) {
            bf16x8 a[2], bfr[2];
            #pragma unroll
            for (int fm = 0; fm < 2; ++fm)
                a[fm] = *(const bf16x8*)(h2 + (wrB*32 + fm*16 + (lane&15))*392 + kt*64 + ks*32 + (lane>>4)*8);
            #pragma unroll
            for (int fn = 0; fn < 2; ++fn) {
                int n = wcB*32 + fn*16 + (lane&15);
                int g = ks*4 + (lane>>4);
                bfr[fn] = *(const bf16x8*)(w3c + n*64 + ((g ^ (n&7)) * 8));
            }
            #pragma unroll
            for (int fm = 0; fm < 2; ++fm)
                #pragma unroll
                for (int fn = 0; fn < 2; ++fn)
                    acc3[fm][fn] = __builtin_amdgcn_mfma_f32_16x16x32_bf16(a[fm], bfr[fn], acc3[fm][fn], 0,0,0);
        }
        __builtin_amdgcn_s_setprio(0);
        __syncthreads();
    }
    #pragma unroll
    for (int fm = 0; fm < 2; ++fm)
        #pragma unroll
        for (int fn = 0; fn < 2; ++fn) {
            int col = wcB*32 + fn*16 + (lane&15);
            float bb = b3[col];
            #pragma unroll
            for (int q = 0; q < 4; ++q) {
                int row = p0 + wrB*32 + fm*16 + (lane>>4)*4 + q;
                out[(size_t)row*128 + col] = acc3[fm][fn][q] + bb;
            }
        }
}

extern "C" void kernel_launch(void* const* d_in, const int* in_sizes, int n_in,
                              void* d_out, int out_size, void* d_ws, size_t ws_size,
                              hipStream_t stream) {
    const float* feat = (const float*)d_in[0];  // [256][768]
    const float* W1   = (const float*)d_in[1];  // [1536][768]
    const float* b1   = (const float*)d_in[2];  // [768]
    const float* W2   = (const float*)d_in[3];  // [768][384]
    const float* b2   = (const float*)d_in[4];  // [384]
    const float* W3   = (const float*)d_in[5];  // [384][128]
    const float* b3   = (const float*)d_in[6];  // [128]
    float* out = (float*)d_out;

    char* ws = (char*)d_ws;
    unsigned short* W2t = (unsigned short*)(ws + 0);        // 384*768*2 = 589,824
    unsigned short* W3t = (unsigned short*)(ws + 589824);   // 128*384*2 =  98,304
    float*          AB  = (float*)        (ws + 688128);    // 256*1536*4 = 1,572,864

    prep_ab_k<<<432, 256, 0, stream>>>(feat, W1, b1, W2, W3, W2t, W3t, AB);
    fused_k<<<255, 1024, 0, stream>>>(AB, W2t, b2, W3t, b3, out);
}